// Round 9
// baseline (706.050 us; speedup 1.0000x reference)
//
#include <hip/hip_runtime.h>
#include <hip/hip_bf16.h>
#include <cstdint>

#define B_ 4
#define SQ_ 128
#define SKV_ 8192
#define H_ 32
#define D_ 128
#define KT 64
#define HD (H_ * D_)

typedef __bf16 bf16x8 __attribute__((ext_vector_type(8)));
typedef float f32x4 __attribute__((ext_vector_type(4)));

union U4B8 { uint4 u; bf16x8 v; };

__device__ inline unsigned f2b_pack(float a, float b){
  unsigned ua = __float_as_uint(a); ua = (ua + 0x7FFFu + ((ua >> 16) & 1u)) >> 16;
  unsigned ub = __float_as_uint(b); ub = (ub + 0x7FFFu + ((ub >> 16) & 1u)) >> 16;
  return (ua & 0xFFFFu) | (ub << 16);
}
__device__ inline unsigned short f2b1(float a){
  unsigned ua = __float_as_uint(a);
  return (unsigned short)((ua + 0x7FFFu + ((ua >> 16) & 1u)) >> 16);
}

// Split-KV attention, KT=64 register-carried double-buffer pipeline.
// Block = 512 threads = 8 waves; each wave owns 16 Q rows.
// LDS 64 KB: K dbuf 2x16K + V^T dbuf 2x16K; P (2KB/wave) OVERLAYS the current
// K buffer after barrier (B) (all K reads done). Per iter: issue 8 prefetch
// loads (pinned) -> QK^T -> (B) -> exp/P/PV -> convert+write buf^1 (vmcnt
// lands here) -> (C). 2 blocks/CU x 8 waves = 16 waves/CU; grid 512 resident.
__global__ __launch_bounds__(512, 4) void mha_split_kernel(
    const float* __restrict__ q, const float* __restrict__ k, const float* __restrict__ v,
    float* __restrict__ Ubase, float* __restrict__ Lbase, float* __restrict__ outp, int nsplit)
{
  __shared__ char smem[64 * 1024] __attribute__((aligned(16)));
  // K0 @0, K1 @16K: [64 keys][128 d] bf16, 256B rows, swz ^((key&7)<<4)
  // V0 @32K, V1 @48K: V^T [128 d][64 keys] bf16, 128B rows, swz ^(((d^(d>>2))&7)<<4)
  // P: per-wave [16][64] bf16, 128B rows, swz ^((row&7)<<4), overlay on K[cur]

  const int tid = threadIdx.x;
  const int w = tid >> 6;
  const int l = tid & 63;
  const int g = l >> 4;      // 16-lane group 0..3
  const int c = l & 15;      // lane within group

  const int bh = blockIdx.x;
  const int split = blockIdx.y;
  const int b = bh >> 5, h = bh & 31;
  const int kps = SKV_ / nsplit;
  const int kv0 = split * kps;
  const int nt = kps / KT;

  const float qscale = 0.08838834764831845f * 1.4426950408889634f; // 1/sqrt(128)*log2(e)

  // ---- Q fragments (A-operand: m=c, k = ks*32 + g*8 + j); wave rows w*16..+15
  bf16x8 qf[4];
  {
    const float* qr = q + (((size_t)b * SQ_ + (w * 16 + c)) * H_ + h) * D_;
#pragma unroll
    for (int ks = 0; ks < 4; ++ks) {
      int d0 = ks * 32 + g * 8;
      float4 x = *(const float4*)(qr + d0);
      float4 y = *(const float4*)(qr + d0 + 4);
      U4B8 t;
      t.u.x = f2b_pack(x.x * qscale, x.y * qscale);
      t.u.y = f2b_pack(x.z * qscale, x.w * qscale);
      t.u.z = f2b_pack(y.x * qscale, y.y * qscale);
      t.u.w = f2b_pack(y.z * qscale, y.w * qscale);
      qf[ks] = t.v;
    }
  }

  f32x4 oacc[8];
#pragma unroll
  for (int ni = 0; ni < 8; ++ni) oacc[ni] = (f32x4)0.0f;
  float lacc[4] = {};

  const float* kbase = k + ((size_t)b * SKV_ + kv0) * HD + (size_t)h * D_;
  const float* vbase = v + ((size_t)b * SKV_ + kv0) * HD + (size_t)h * D_;

  // staging indices (512 threads, 64-key tile):
  const int krow = tid >> 5;           // 0..15
  const int d4s  = (tid & 31) * 4;     // float offset within the 128-d row

  float4 kreg[4], vreg[4];

  // ---- prologue: load + convert + store tile 0 into buf 0
  {
#pragma unroll
    for (int it = 0; it < 4; ++it)
      kreg[it] = *(const float4*)(kbase + (size_t)(it * 16 + krow) * HD + d4s);
#pragma unroll
    for (int it = 0; it < 2; ++it) {
      const float* va = vbase + (size_t)(2 * (it * 16 + krow)) * HD + d4s;
      vreg[2 * it]     = *(const float4*)va;
      vreg[2 * it + 1] = *(const float4*)(va + HD);
    }
#pragma unroll
    for (int it = 0; it < 4; ++it) {
      int key = it * 16 + krow;
      uint2 kw = make_uint2(f2b_pack(kreg[it].x, kreg[it].y), f2b_pack(kreg[it].z, kreg[it].w));
      *(uint2*)(smem + key * 256 + ((d4s * 2) ^ ((key & 7) << 4))) = kw;
    }
#pragma unroll
    for (int it = 0; it < 2; ++it) {
      int kp = it * 16 + krow;
      float va[4] = {vreg[2*it].x, vreg[2*it].y, vreg[2*it].z, vreg[2*it].w};
      float vb[4] = {vreg[2*it+1].x, vreg[2*it+1].y, vreg[2*it+1].z, vreg[2*it+1].w};
#pragma unroll
      for (int i = 0; i < 4; ++i) {
        int d = d4s + i;
        *(unsigned*)(smem + 32768 + d * 128 + ((kp * 4) ^ (((d ^ (d >> 2)) & 7) << 4))) =
            f2b_pack(va[i], vb[i]);
      }
    }
  }
  __syncthreads();

  for (int t = 0; t < nt; ++t) {
    const int cur = t & 1;
    char* kc = smem + cur * 16384;
    char* vc = smem + 32768 + cur * 16384;
    char* pl = kc + w * 2048;          // P overlay on current K buffer

    // ---- issue prefetch loads for tile t+1 (8 x float4, held through compute)
    if (t + 1 < nt) {
      const float* kt = kbase + (size_t)(t + 1) * KT * HD;
      const float* vt = vbase + (size_t)(t + 1) * KT * HD;
#pragma unroll
      for (int it = 0; it < 4; ++it)
        kreg[it] = *(const float4*)(kt + (size_t)(it * 16 + krow) * HD + d4s);
#pragma unroll
      for (int it = 0; it < 2; ++it) {
        const float* va = vt + (size_t)(2 * (it * 16 + krow)) * HD + d4s;
        vreg[2 * it]     = *(const float4*)va;
        vreg[2 * it + 1] = *(const float4*)(va + HD);
      }
    }
    __builtin_amdgcn_sched_barrier(0);  // pin load issue above compute

    __builtin_amdgcn_s_setprio(1);
    // ---- S = Q K^T (16 rows x 64 keys: 16 MFMA)
    f32x4 sacc[4];
#pragma unroll
    for (int ni = 0; ni < 4; ++ni) sacc[ni] = (f32x4)0.0f;
#pragma unroll
    for (int ni = 0; ni < 4; ++ni) {
      int key = ni * 16 + c;
      int rb = key * 256;
      int sw = (key & 7) << 4;
#pragma unroll
      for (int ks = 0; ks < 4; ++ks) {
        U4B8 bf;
        bf.u = *(uint4*)(kc + rb + ((ks * 64 + g * 16) ^ sw));
        sacc[ni] = __builtin_amdgcn_mfma_f32_16x16x32_bf16(qf[ks], bf.v, sacc[ni], 0, 0, 0);
      }
    }
    __builtin_amdgcn_s_setprio(0);
    __syncthreads();   // (B) all K[cur] reads done -> P may overwrite K region

    __builtin_amdgcn_s_setprio(1);
    // ---- p = exp2(s) -> P overlay (wave-private; in-wave lgkm ordering)
#pragma unroll
    for (int ni = 0; ni < 4; ++ni) {
#pragma unroll
      for (int r = 0; r < 4; ++r) {
        float p = exp2f(sacc[ni][r]);
        lacc[r] += p;
        int row = g * 4 + r;
        int col = ni * 16 + c;
        *(unsigned short*)(pl + row * 128 + ((col * 2) ^ ((row & 7) << 4))) = f2b1(p);
      }
    }

    // ---- O += P V (2 K-steps x 8 d-blocks = 16 MFMA)
#pragma unroll
    for (int ks2 = 0; ks2 < 2; ++ks2) {
      U4B8 ap;
      ap.u = *(uint4*)(pl + c * 128 + ((ks2 * 64 + g * 16) ^ ((c & 7) << 4)));
#pragma unroll
      for (int ni = 0; ni < 8; ++ni) {
        int d = ni * 16 + c;
        U4B8 bv;
        bv.u = *(uint4*)(vc + d * 128 + ((ks2 * 64 + g * 16) ^ (((d ^ (d >> 2)) & 7) << 4)));
        oacc[ni] = __builtin_amdgcn_mfma_f32_16x16x32_bf16(ap.v, bv.v, oacc[ni], 0, 0, 0);
      }
    }
    __builtin_amdgcn_s_setprio(0);

    // ---- convert + write prefetched tile into buf[cur^1] (vmcnt lands here)
    if (t + 1 < nt) {
      char* kn = smem + (cur ^ 1) * 16384;
      char* vn = smem + 32768 + (cur ^ 1) * 16384;
#pragma unroll
      for (int it = 0; it < 4; ++it) {
        int key = it * 16 + krow;
        uint2 kw = make_uint2(f2b_pack(kreg[it].x, kreg[it].y), f2b_pack(kreg[it].z, kreg[it].w));
        *(uint2*)(kn + key * 256 + ((d4s * 2) ^ ((key & 7) << 4))) = kw;
      }
#pragma unroll
      for (int it = 0; it < 2; ++it) {
        int kp = it * 16 + krow;
        float va[4] = {vreg[2*it].x, vreg[2*it].y, vreg[2*it].z, vreg[2*it].w};
        float vb[4] = {vreg[2*it+1].x, vreg[2*it+1].y, vreg[2*it+1].z, vreg[2*it+1].w};
#pragma unroll
        for (int i = 0; i < 4; ++i) {
          int d = d4s + i;
          *(unsigned*)(vn + d * 128 + ((kp * 4) ^ (((d ^ (d >> 2)) & 7) << 4))) =
              f2b_pack(va[i], vb[i]);
        }
      }
    }
    __syncthreads();   // (C) staged writes visible; buf[cur] fully consumed
  }

  // ---- reduce l across the 16 lanes sharing each row
#pragma unroll
  for (int r = 0; r < 4; ++r) {
    float s = lacc[r];
    s += __shfl_xor(s, 1, 16);
    s += __shfl_xor(s, 2, 16);
    s += __shfl_xor(s, 4, 16);
    s += __shfl_xor(s, 8, 16);
    lacc[r] = s;
  }

  if (nsplit == 1) {
    float* op = outp + (((size_t)b * SQ_) * H_ + h) * D_;
#pragma unroll
    for (int r = 0; r < 4; ++r) {
      int row = w * 16 + g * 4 + r;
      float inv = 1.0f / lacc[r];
#pragma unroll
      for (int ni = 0; ni < 8; ++ni) {
        op[(size_t)row * HD + ni * 16 + c] = oacc[ni][r] * inv;
      }
    }
  } else {
    float* Up = Ubase + ((size_t)split * 128 + bh) * (SQ_ * D_);
#pragma unroll
    for (int r = 0; r < 4; ++r) {
      int row = w * 16 + g * 4 + r;
#pragma unroll
      for (int ni = 0; ni < 8; ++ni) {
        Up[(size_t)row * D_ + ni * 16 + c] = oacc[ni][r];
      }
      if (c == 0) Lbase[((size_t)split * 128 + bh) * SQ_ + row] = lacc[r];
    }
  }
}

// Combine kernel: out = sum_s U_s / sum_s l_s, layout [b,h,q,d] -> [b,q,h,d]
__global__ void mha_combine_kernel(const float* __restrict__ Ubase, const float* __restrict__ Lbase,
                                   float* __restrict__ outp, int nsplit) {
  int idx = blockIdx.x * 256 + threadIdx.x;   // over BH*SQ*D = 2M
  int rowlin = idx >> 7;                       // bh*128 + row
  int d = idx & 127;
  float su = 0.f, sl = 0.f;
  for (int s = 0; s < nsplit; ++s) {
    su += Ubase[(size_t)s * (128 * SQ_ * D_) + idx];
    sl += Lbase[(size_t)s * (128 * SQ_) + rowlin];
  }
  int bh = rowlin >> 7, row = rowlin & 127;
  int b = bh >> 5, h = bh & 31;
  outp[(((size_t)b * SQ_ + row) * H_ + h) * D_ + d] = su / sl;
}

extern "C" void kernel_launch(void* const* d_in, const int* in_sizes, int n_in,
                              void* d_out, int out_size, void* d_ws, size_t ws_size,
                              hipStream_t stream) {
  const float* q = (const float*)d_in[0];
  const float* k = (const float*)d_in[1];
  const float* v = (const float*)d_in[2];
  float* outp = (float*)d_out;

  const size_t per_split = (size_t)128 * SQ_ * D_ * 4 + (size_t)128 * SQ_ * 4; // U + l
  int nsplit = 1;
  if (ws_size >= 4 * per_split) nsplit = 4;       // 512 blocks of 512 thr = 2/CU resident
  else if (ws_size >= 2 * per_split) nsplit = 2;

  float* Ubase = (float*)d_ws;
  float* Lbase = Ubase + (size_t)nsplit * 128 * SQ_ * D_;

  dim3 grid(128, nsplit);
  mha_split_kernel<<<grid, 512, 0, stream>>>(q, k, v, Ubase, Lbase, outp, nsplit);
  if (nsplit > 1) {
    mha_combine_kernel<<<(128 * SQ_ * D_) / 256, 256, 0, stream>>>(Ubase, Lbase, outp, nsplit);
  }
}

// Round 10
// 221.559 us; speedup vs baseline: 3.1867x; 3.1867x over previous
//
#include <hip/hip_runtime.h>
#include <hip/hip_bf16.h>
#include <cstdint>

#define B_ 4
#define SQ_ 128
#define SKV_ 8192
#define H_ 32
#define D_ 128
#define KT 32
#define HD (H_ * D_)

typedef __bf16 bf16x8 __attribute__((ext_vector_type(8)));
typedef float f32x4 __attribute__((ext_vector_type(4)));

union U4B8 { uint4 u; bf16x8 v; };

__device__ inline unsigned f2b_pack(float a, float b){
  unsigned ua = __float_as_uint(a); ua = (ua + 0x7FFFu + ((ua >> 16) & 1u)) >> 16;
  unsigned ub = __float_as_uint(b); ub = (ub + 0x7FFFu + ((ub >> 16) & 1u)) >> 16;
  return (ua & 0xFFFFu) | (ub << 16);
}
__device__ inline unsigned short f2b1(float a){
  unsigned ua = __float_as_uint(a);
  return (unsigned short)((ua + 0x7FFFu + ((ua >> 16) & 1u)) >> 16);
}

// Split-KV attention, KT=32, depth-2 register prefetch + LDS double buffer.
// Block = 512 threads = 8 waves; each wave owns 16 Q rows.
// Iter t: issue loads(tile t+2) into regbuf X (pinned by sched_barrier) ->
// compute tile t from LDS[t&1] -> write regbuf Y (tile t+1, issued at t-1,
// ~2 iters of latency cover) into LDS[(t+1)&1] -> one barrier.
// Loop unrolled x2 so all reg-buffer / LDS indices are compile-time.
// LDS 40KB: K dbuf 2x8K + V^T dbuf 2x8K + P 8K(1K/wave). bounds (512,2):
// avoid the (512,4) 64-VGPR clamp (R9 spill); est ~88 arch + 32 acc = 120
// total -> 4 waves/SIMD, 2 blocks/CU, grid 512 fully resident.
__global__ __launch_bounds__(512, 2) void mha_split_kernel(
    const float* __restrict__ q, const float* __restrict__ k, const float* __restrict__ v,
    float* __restrict__ Ubase, float* __restrict__ Lbase, float* __restrict__ outp, int nsplit)
{
  __shared__ char smem[40 * 1024] __attribute__((aligned(16)));
  // K0 @0, K1 @8K:   [32 keys][128 d] bf16, 256B rows, swz ^((key&7)<<4)
  // V0 @16K, V1@24K: V^T [128 d][32 keys] bf16, 64B rows, 4-slot swz
  // P  @32K: per-wave [16][32] bf16, 64B rows, 4-slot swz

  const int tid = threadIdx.x;
  const int w = tid >> 6;
  const int l = tid & 63;
  const int g = l >> 4;      // 16-lane group 0..3
  const int c = l & 15;      // lane within group
  char* Plds = smem + 32768 + w * 1024;

  const int bh = blockIdx.x;
  const int split = blockIdx.y;
  const int b = bh >> 5, h = bh & 31;
  const int kps = SKV_ / nsplit;
  const int kv0 = split * kps;
  const int nt = kps / KT;   // 64 for nsplit=4 (always even)

  const float qscale = 0.08838834764831845f * 1.4426950408889634f; // 1/sqrt(128)*log2(e)

  // ---- Q fragments (A-operand: m=c, k = ks*32 + g*8 + j)
  bf16x8 qf[4];
  {
    const float* qr = q + (((size_t)b * SQ_ + (w * 16 + c)) * H_ + h) * D_;
#pragma unroll
    for (int ks = 0; ks < 4; ++ks) {
      int d0 = ks * 32 + g * 8;
      float4 x = *(const float4*)(qr + d0);
      float4 y = *(const float4*)(qr + d0 + 4);
      U4B8 t;
      t.u.x = f2b_pack(x.x * qscale, x.y * qscale);
      t.u.y = f2b_pack(x.z * qscale, x.w * qscale);
      t.u.z = f2b_pack(y.x * qscale, y.y * qscale);
      t.u.w = f2b_pack(y.z * qscale, y.w * qscale);
      qf[ks] = t.v;
    }
  }

  f32x4 oacc[8];
#pragma unroll
  for (int ni = 0; ni < 8; ++ni) oacc[ni] = (f32x4)0.0f;
  float lacc[4] = {};

  const float* kbase = k + ((size_t)b * SKV_ + kv0) * HD + (size_t)h * D_;
  const float* vbase = v + ((size_t)b * SKV_ + kv0) * HD + (size_t)h * D_;

  // staging indices (512 threads, 32-key tile)
  const int key_s = tid >> 4;          // 0..31 (K row)
  const int d8_s  = (tid & 15) * 8;    // K: float offset
  const int kp_s  = tid >> 5;          // 0..15 (V key pair)
  const int d4_s  = (tid & 31) * 4;    // V: float offset
  const int koff_w = key_s * 256 + ((d8_s * 2) ^ ((key_s & 7) << 4));

  float4 kA0, kA1, vA0, vA1;   // reg buffer A
  float4 kB0, kB1, vB0, vB1;   // reg buffer B

// ---- staging helpers (macros keep everything statically indexed) ----
#define ISSUE(T, K0r, K1r, V0r, V1r)                                          \
  {                                                                           \
    const float* kt_ = kbase + (size_t)(T) * KT * HD + (size_t)key_s * HD + d8_s; \
    K0r = *(const float4*)(kt_);                                              \
    K1r = *(const float4*)(kt_ + 4);                                          \
    const float* vt_ = vbase + (size_t)(T) * KT * HD + (size_t)(kp_s * 2) * HD + d4_s; \
    V0r = *(const float4*)(vt_);                                              \
    V1r = *(const float4*)(vt_ + HD);                                         \
  }

#define WRITE_LDS(KDST, VDST, K0r, K1r, V0r, V1r)                             \
  {                                                                           \
    uint4 kw_;                                                                \
    kw_.x = f2b_pack(K0r.x, K0r.y); kw_.y = f2b_pack(K0r.z, K0r.w);           \
    kw_.z = f2b_pack(K1r.x, K1r.y); kw_.w = f2b_pack(K1r.z, K1r.w);           \
    *(uint4*)((KDST) + koff_w) = kw_;                                         \
    float va0_ = V0r.x, va1_ = V0r.y, va2_ = V0r.z, va3_ = V0r.w;             \
    float vb0_ = V1r.x, vb1_ = V1r.y, vb2_ = V1r.z, vb3_ = V1r.w;             \
    int d0_ = d4_s;                                                           \
    int slotbase_ = (kp_s >> 2);                                              \
    int s0_ = ((slotbase_ ^ ((d0_ >> 2) & 3)) & 3);                           \
    *(unsigned*)((VDST) + (d0_ + 0) * 64 + s0_ * 16 + (kp_s & 3) * 4) = f2b_pack(va0_, vb0_); \
    *(unsigned*)((VDST) + (d0_ + 1) * 64 + s0_ * 16 + (kp_s & 3) * 4) = f2b_pack(va1_, vb1_); \
    *(unsigned*)((VDST) + (d0_ + 2) * 64 + s0_ * 16 + (kp_s & 3) * 4) = f2b_pack(va2_, vb2_); \
    *(unsigned*)((VDST) + (d0_ + 3) * 64 + s0_ * 16 + (kp_s & 3) * 4) = f2b_pack(va3_, vb3_); \
  }

#define COMPUTE(KC, VC)                                                       \
  {                                                                           \
    __builtin_amdgcn_s_setprio(1);                                            \
    f32x4 s0_ = (f32x4)0.0f, s1_ = (f32x4)0.0f;                               \
    _Pragma("unroll")                                                         \
    for (int ks = 0; ks < 4; ++ks) {                                          \
      U4B8 bf0_, bf1_;                                                        \
      int sw0_ = (c & 7) << 4;                                                \
      bf0_.u = *(uint4*)((KC) + c * 256 + ((ks * 64 + g * 16) ^ sw0_));       \
      int key1_ = 16 + c;                                                     \
      bf1_.u = *(uint4*)((KC) + key1_ * 256 + ((ks * 64 + g * 16) ^ sw0_));   \
      s0_ = __builtin_amdgcn_mfma_f32_16x16x32_bf16(qf[ks], bf0_.v, s0_, 0, 0, 0); \
      s1_ = __builtin_amdgcn_mfma_f32_16x16x32_bf16(qf[ks], bf1_.v, s1_, 0, 0, 0); \
    }                                                                         \
    _Pragma("unroll")                                                         \
    for (int r = 0; r < 4; ++r) {                                             \
      float p0_ = exp2f(s0_[r]); lacc[r] += p0_;                              \
      float p1_ = exp2f(s1_[r]); lacc[r] += p1_;                              \
      int row_ = g * 4 + r;                                                   \
      int col0_ = c, col1_ = 16 + c;                                          \
      *(unsigned short*)(Plds + row_ * 64 + ((((col0_ >> 3) ^ g) & 3) * 16) + (col0_ & 7) * 2) = f2b1(p0_); \
      *(unsigned short*)(Plds + row_ * 64 + ((((col1_ >> 3) ^ g) & 3) * 16) + (col1_ & 7) * 2) = f2b1(p1_); \
    }                                                                         \
    {                                                                         \
      const int slot_ = ((g ^ (c >> 2)) & 3) * 16;                            \
      U4B8 ap_;                                                               \
      ap_.u = *(uint4*)(Plds + c * 64 + slot_);                               \
      _Pragma("unroll")                                                       \
      for (int ni = 0; ni < 8; ++ni) {                                        \
        int d_ = ni * 16 + c;                                                 \
        U4B8 bv_;                                                             \
        bv_.u = *(uint4*)((VC) + d_ * 64 + slot_);                            \
        oacc[ni] = __builtin_amdgcn_mfma_f32_16x16x32_bf16(ap_.v, bv_.v, oacc[ni], 0, 0, 0); \
      }                                                                       \
    }                                                                         \
    __builtin_amdgcn_s_setprio(0);                                            \
  }

  char* const K0 = smem;
  char* const K1 = smem + 8192;
  char* const V0 = smem + 16384;
  char* const V1 = smem + 24576;

  // ---- prologue: tile0 -> LDS[0] (direct), then issue tile1 -> bufA
  ISSUE(0, kA0, kA1, vA0, vA1);
  WRITE_LDS(K0, V0, kA0, kA1, vA0, vA1);   // vmcnt wait here (unavoidable once)
  ISSUE(1, kA0, kA1, vA0, vA1);            // regs free after the write consumed them
  __syncthreads();

  for (int tp = 0; tp < nt; tp += 2) {
    // ===== even iter t=tp: compute LDS0; issue t+2 -> B; write A(t+1) -> LDS1
    if (tp + 2 < nt) ISSUE(tp + 2, kB0, kB1, vB0, vB1);
    __builtin_amdgcn_sched_barrier(0);
    COMPUTE(K0, V0);
    WRITE_LDS(K1, V1, kA0, kA1, vA0, vA1);  // tile tp+1 (issued 1-2 iters ago)
    __syncthreads();

    // ===== odd iter t=tp+1: compute LDS1; issue t+2 -> A; write B(t+2? no: t+1=tp+2) -> LDS0
    if (tp + 3 < nt) ISSUE(tp + 3, kA0, kA1, vA0, vA1);
    __builtin_amdgcn_sched_barrier(0);
    COMPUTE(K1, V1);
    if (tp + 2 < nt) {
      WRITE_LDS(K0, V0, kB0, kB1, vB0, vB1);  // tile tp+2, issued at even iter top
    }
    __syncthreads();
  }

#undef ISSUE
#undef WRITE_LDS
#undef COMPUTE

  // ---- reduce l across the 16 lanes sharing each row
#pragma unroll
  for (int r = 0; r < 4; ++r) {
    float s = lacc[r];
    s += __shfl_xor(s, 1, 16);
    s += __shfl_xor(s, 2, 16);
    s += __shfl_xor(s, 4, 16);
    s += __shfl_xor(s, 8, 16);
    lacc[r] = s;
  }

  if (nsplit == 1) {
    float* op = outp + (((size_t)b * SQ_) * H_ + h) * D_;
#pragma unroll
    for (int r = 0; r < 4; ++r) {
      int row = w * 16 + g * 4 + r;
      float inv = 1.0f / lacc[r];
#pragma unroll
      for (int ni = 0; ni < 8; ++ni) {
        op[(size_t)row * HD + ni * 16 + c] = oacc[ni][r] * inv;
      }
    }
  } else {
    float* Up = Ubase + ((size_t)split * 128 + bh) * (SQ_ * D_);
#pragma unroll
    for (int r = 0; r < 4; ++r) {
      int row = w * 16 + g * 4 + r;
#pragma unroll
      for (int ni = 0; ni < 8; ++ni) {
        Up[(size_t)row * D_ + ni * 16 + c] = oacc[ni][r];
      }
      if (c == 0) Lbase[((size_t)split * 128 + bh) * SQ_ + row] = lacc[r];
    }
  }
}

// Combine kernel: out = sum_s U_s / sum_s l_s, layout [b,h,q,d] -> [b,q,h,d]
__global__ void mha_combine_kernel(const float* __restrict__ Ubase, const float* __restrict__ Lbase,
                                   float* __restrict__ outp, int nsplit) {
  int idx = blockIdx.x * 256 + threadIdx.x;   // over BH*SQ*D = 2M
  int rowlin = idx >> 7;                       // bh*128 + row
  int d = idx & 127;
  float su = 0.f, sl = 0.f;
  for (int s = 0; s < nsplit; ++s) {
    su += Ubase[(size_t)s * (128 * SQ_ * D_) + idx];
    sl += Lbase[(size_t)s * (128 * SQ_) + rowlin];
  }
  int bh = rowlin >> 7, row = rowlin & 127;
  int b = bh >> 5, h = bh & 31;
  outp[(((size_t)b * SQ_ + row) * H_ + h) * D_ + d] = su / sl;
}

extern "C" void kernel_launch(void* const* d_in, const int* in_sizes, int n_in,
                              void* d_out, int out_size, void* d_ws, size_t ws_size,
                              hipStream_t stream) {
  const float* q = (const float*)d_in[0];
  const float* k = (const float*)d_in[1];
  const float* v = (const float*)d_in[2];
  float* outp = (float*)d_out;

  const size_t per_split = (size_t)128 * SQ_ * D_ * 4 + (size_t)128 * SQ_ * 4; // U + l
  int nsplit = 1;
  if (ws_size >= 4 * per_split) nsplit = 4;       // 512 blocks of 512 thr = 2/CU resident
  else if (ws_size >= 2 * per_split) nsplit = 2;

  float* Ubase = (float*)d_ws;
  float* Lbase = Ubase + (size_t)nsplit * 128 * SQ_ * D_;

  dim3 grid(128, nsplit);
  mha_split_kernel<<<grid, 512, 0, stream>>>(q, k, v, Ubase, Lbase, outp, nsplit);
  if (nsplit > 1) {
    mha_combine_kernel<<<(128 * SQ_ * D_) / 256, 256, 0, stream>>>(Ubase, Lbase, outp, nsplit);
  }
}

// Round 11
// 199.159 us; speedup vs baseline: 3.5452x; 1.1125x over previous
//
#include <hip/hip_runtime.h>
#include <hip/hip_bf16.h>
#include <cstdint>

#define B_ 4
#define SQ_ 128
#define SKV_ 8192
#define H_ 32
#define D_ 128
#define KT 32
#define HD (H_ * D_)

typedef __bf16 bf16x8 __attribute__((ext_vector_type(8)));
typedef float f32x4 __attribute__((ext_vector_type(4)));

union U4B8 { uint4 u; bf16x8 v; };

__device__ inline unsigned f2b_pack(float a, float b){
  unsigned ua = __float_as_uint(a); ua = (ua + 0x7FFFu + ((ua >> 16) & 1u)) >> 16;
  unsigned ub = __float_as_uint(b); ub = (ub + 0x7FFFu + ((ub >> 16) & 1u)) >> 16;
  return (ua & 0xFFFFu) | (ub << 16);
}
__device__ inline unsigned short f2b1(float a){
  unsigned ua = __float_as_uint(a);
  return (unsigned short)((ua + 0x7FFFu + ((ua >> 16) & 1u)) >> 16);
}

// Split-KV attention, R8 structure with EARLY prefetch issue.
// Block = 512 threads = 8 waves; each wave owns 16 Q rows. KT=32 keys/tile.
// Iter t: compute tile t from LDS[t&1] -> write regs (tile t+1, issued at the
// END of iter t-1, in flight across the barrier + this whole compute phase)
// into LDS[(t+1)&1] -> immediately re-issue loads for tile t+2 into the same
// regs -> sched_barrier -> __syncthreads. Loads target registers only, so the
// barrier needs no vmcnt drain; the window now covers barrier-wait + compute.
// LDS 40KB: K dbuf 2x8K + V^T dbuf 2x8K + P 8K (1K/wave, dedicated).
// launch_bounds(512,4) proven in R8: 64 arch VGPR + 32 acc fits, no spill,
// 2 blocks/CU x 8 waves = 16 waves/CU, grid 512 fully resident.
__global__ __launch_bounds__(512, 4) void mha_split_kernel(
    const float* __restrict__ q, const float* __restrict__ k, const float* __restrict__ v,
    float* __restrict__ Ubase, float* __restrict__ Lbase, float* __restrict__ outp, int nsplit)
{
  __shared__ char smem[40 * 1024] __attribute__((aligned(16)));
  // K0 @0, K1 @8K: [32 keys][128 d] bf16, 256B rows, slot swz ^((key&7)<<4)
  // V0 @16K, V1 @24K: V^T [128 d][32 keys] bf16, 64B rows, slot swz ^((d>>2)&3)
  // P  @32K: per-wave [16 rows][32 cols] bf16, 64B rows, slot swz ^((row>>2)&3)

  const int tid = threadIdx.x;
  const int w = tid >> 6;
  const int l = tid & 63;
  const int g = l >> 4;      // 16-lane group 0..3
  const int c = l & 15;      // lane within group
  char* Plds = smem + 32768 + w * 1024;

  const int bh = blockIdx.x;
  const int split = blockIdx.y;
  const int b = bh >> 5, h = bh & 31;
  const int kps = SKV_ / nsplit;
  const int kv0 = split * kps;
  const int nt = kps / KT;

  const float qscale = 0.08838834764831845f * 1.4426950408889634f; // 1/sqrt(128)*log2(e)

  // ---- Q fragments (A-operand: m=c, k = ks*32 + g*8 + j); wave rows w*16..w*16+15
  bf16x8 qf[4];
  {
    const float* qr = q + (((size_t)b * SQ_ + (w * 16 + c)) * H_ + h) * D_;
#pragma unroll
    for (int ks = 0; ks < 4; ++ks) {
      int d0 = ks * 32 + g * 8;
      float4 x = *(const float4*)(qr + d0);
      float4 y = *(const float4*)(qr + d0 + 4);
      U4B8 t;
      t.u.x = f2b_pack(x.x * qscale, x.y * qscale);
      t.u.y = f2b_pack(x.z * qscale, x.w * qscale);
      t.u.z = f2b_pack(y.x * qscale, y.y * qscale);
      t.u.w = f2b_pack(y.z * qscale, y.w * qscale);
      qf[ks] = t.v;
    }
  }

  f32x4 oacc[8];
#pragma unroll
  for (int ni = 0; ni < 8; ++ni) oacc[ni] = (f32x4)0.0f;
  float lacc[4] = {};

  const float* kbase = k + ((size_t)b * SKV_ + kv0) * HD + (size_t)h * D_;
  const float* vbase = v + ((size_t)b * SKV_ + kv0) * HD + (size_t)h * D_;

  // staging assignments (512 threads, 32-key tile)
  const int key_s = tid >> 4;          // 0..31  (K: one key row, 8 floats)
  const int d8_s  = (tid & 15) * 8;    // K: d offset
  const int kp_s  = tid >> 5;          // 0..15  (V: key pair, 4 d-values x 2 keys)
  const int d4_s  = (tid & 31) * 4;    // V: d offset
  const int koff_w = key_s * 256 + ((d8_s * 2) ^ ((key_s & 7) << 4));

  float4 kreg0, kreg1, vreg0, vreg1;

  // ---- prologue: stage tile 0 into buf 0, then issue tile 1 into regs
  {
    const float* kt = kbase + (size_t)key_s * HD + d8_s;
    kreg0 = *(const float4*)(kt);
    kreg1 = *(const float4*)(kt + 4);
    const float* vt = vbase + (size_t)(kp_s * 2) * HD + d4_s;
    vreg0 = *(const float4*)(vt);
    vreg1 = *(const float4*)(vt + HD);
    uint4 kw;
    kw.x = f2b_pack(kreg0.x, kreg0.y); kw.y = f2b_pack(kreg0.z, kreg0.w);
    kw.z = f2b_pack(kreg1.x, kreg1.y); kw.w = f2b_pack(kreg1.z, kreg1.w);
    *(uint4*)(smem + koff_w) = kw;
    float va[4] = {vreg0.x, vreg0.y, vreg0.z, vreg0.w};
    float vb[4] = {vreg1.x, vreg1.y, vreg1.z, vreg1.w};
#pragma unroll
    for (int i = 0; i < 4; ++i) {
      int d = d4_s + i;
      int slot = ((kp_s >> 2) ^ ((d >> 2) & 3)) & 3;
      *(unsigned*)(smem + 16384 + d * 64 + slot * 16 + (kp_s & 3) * 4) = f2b_pack(va[i], vb[i]);
    }
    // issue tile 1 loads (consumed by WRITE at end of iter 0)
    const float* kt1 = kbase + (size_t)KT * HD + (size_t)key_s * HD + d8_s;
    kreg0 = *(const float4*)(kt1);
    kreg1 = *(const float4*)(kt1 + 4);
    const float* vt1 = vbase + (size_t)KT * HD + (size_t)(kp_s * 2) * HD + d4_s;
    vreg0 = *(const float4*)(vt1);
    vreg1 = *(const float4*)(vt1 + HD);
  }
  __builtin_amdgcn_sched_barrier(0);
  __syncthreads();

  for (int t = 0; t < nt; ++t) {
    const int cur = t & 1;
    char* kc = smem + cur * 8192;
    char* vc = smem + 16384 + cur * 8192;

    __builtin_amdgcn_s_setprio(1);
    // ---- S = Q K^T (16 rows x 32 keys: 8 MFMA)
    f32x4 sacc[2];
#pragma unroll
    for (int ni = 0; ni < 2; ++ni) sacc[ni] = (f32x4)0.0f;
#pragma unroll
    for (int ni = 0; ni < 2; ++ni) {
      int key = ni * 16 + c;
      int rb = key * 256;
      int sw = (key & 7) << 4;
#pragma unroll
      for (int ks = 0; ks < 4; ++ks) {
        U4B8 bf;
        bf.u = *(uint4*)(kc + rb + ((ks * 64 + g * 16) ^ sw));
        sacc[ni] = __builtin_amdgcn_mfma_f32_16x16x32_bf16(qf[ks], bf.v, sacc[ni], 0, 0, 0);
      }
    }

    // ---- p = exp2(s) -> P (wave-private; in-wave lgkm ordering, no barrier)
#pragma unroll
    for (int ni = 0; ni < 2; ++ni) {
#pragma unroll
      for (int r = 0; r < 4; ++r) {
        float p = exp2f(sacc[ni][r]);
        lacc[r] += p;
        int row = g * 4 + r;
        int col = ni * 16 + c;
        int off = row * 64 + ((((col >> 3) ^ g) & 3) * 16) + (col & 7) * 2;
        *(unsigned short*)(Plds + off) = f2b1(p);
      }
    }

    // ---- O += P V (one K=32 step x 8 d-blocks)
    {
      const int slot = ((g ^ (c >> 2)) & 3) * 16;
      U4B8 ap;
      ap.u = *(uint4*)(Plds + c * 64 + slot);
#pragma unroll
      for (int ni = 0; ni < 8; ++ni) {
        int d = ni * 16 + c;
        U4B8 bv;
        bv.u = *(uint4*)(vc + d * 64 + slot);
        oacc[ni] = __builtin_amdgcn_mfma_f32_16x16x32_bf16(ap.v, bv.v, oacc[ni], 0, 0, 0);
      }
    }
    __builtin_amdgcn_s_setprio(0);

    // ---- convert + write tile t+1 regs into buf[cur^1] (vmcnt wait lands here;
    //      loads were issued at the end of iter t-1 -> ~barrier+compute of cover)
    if (t + 1 < nt) {
      char* kn = smem + (cur ^ 1) * 8192;
      char* vn = smem + 16384 + (cur ^ 1) * 8192;
      uint4 kw;
      kw.x = f2b_pack(kreg0.x, kreg0.y); kw.y = f2b_pack(kreg0.z, kreg0.w);
      kw.z = f2b_pack(kreg1.x, kreg1.y); kw.w = f2b_pack(kreg1.z, kreg1.w);
      *(uint4*)(kn + koff_w) = kw;
      float va[4] = {vreg0.x, vreg0.y, vreg0.z, vreg0.w};
      float vb[4] = {vreg1.x, vreg1.y, vreg1.z, vreg1.w};
#pragma unroll
      for (int i = 0; i < 4; ++i) {
        int d = d4_s + i;
        int slot = ((kp_s >> 2) ^ ((d >> 2) & 3)) & 3;
        *(unsigned*)(vn + d * 64 + slot * 16 + (kp_s & 3) * 4) = f2b_pack(va[i], vb[i]);
      }
    }

    // ---- EARLY issue of tile t+2 loads into the just-freed regs; they stay
    //      in flight across the barrier and all of iter t+1's compute.
    if (t + 2 < nt) {
      const float* kt = kbase + (size_t)(t + 2) * KT * HD + (size_t)key_s * HD + d8_s;
      kreg0 = *(const float4*)(kt);
      kreg1 = *(const float4*)(kt + 4);
      const float* vt = vbase + (size_t)(t + 2) * KT * HD + (size_t)(kp_s * 2) * HD + d4_s;
      vreg0 = *(const float4*)(vt);
      vreg1 = *(const float4*)(vt + HD);
    }
    __builtin_amdgcn_sched_barrier(0);  // pin issue above the barrier
    __syncthreads();   // staged writes visible; all reads of buf[cur] done
  }

  // ---- reduce l across the 16 lanes sharing each row
#pragma unroll
  for (int r = 0; r < 4; ++r) {
    float s = lacc[r];
    s += __shfl_xor(s, 1, 16);
    s += __shfl_xor(s, 2, 16);
    s += __shfl_xor(s, 4, 16);
    s += __shfl_xor(s, 8, 16);
    lacc[r] = s;
  }

  if (nsplit == 1) {
    float* op = outp + (((size_t)b * SQ_) * H_ + h) * D_;
#pragma unroll
    for (int r = 0; r < 4; ++r) {
      int row = w * 16 + g * 4 + r;
      float inv = 1.0f / lacc[r];
#pragma unroll
      for (int ni = 0; ni < 8; ++ni) {
        op[(size_t)row * HD + ni * 16 + c] = oacc[ni][r] * inv;
      }
    }
  } else {
    float* Up = Ubase + ((size_t)split * 128 + bh) * (SQ_ * D_);
#pragma unroll
    for (int r = 0; r < 4; ++r) {
      int row = w * 16 + g * 4 + r;
#pragma unroll
      for (int ni = 0; ni < 8; ++ni) {
        Up[(size_t)row * D_ + ni * 16 + c] = oacc[ni][r];
      }
      if (c == 0) Lbase[((size_t)split * 128 + bh) * SQ_ + row] = lacc[r];
    }
  }
}

// Combine kernel: out = sum_s U_s / sum_s l_s, layout [b,h,q,d] -> [b,q,h,d]
__global__ void mha_combine_kernel(const float* __restrict__ Ubase, const float* __restrict__ Lbase,
                                   float* __restrict__ outp, int nsplit) {
  int idx = blockIdx.x * 256 + threadIdx.x;   // over BH*SQ*D = 2M
  int rowlin = idx >> 7;                       // bh*128 + row
  int d = idx & 127;
  float su = 0.f, sl = 0.f;
  for (int s = 0; s < nsplit; ++s) {
    su += Ubase[(size_t)s * (128 * SQ_ * D_) + idx];
    sl += Lbase[(size_t)s * (128 * SQ_) + rowlin];
  }
  int bh = rowlin >> 7, row = rowlin & 127;
  int b = bh >> 5, h = bh & 31;
  outp[(((size_t)b * SQ_ + row) * H_ + h) * D_ + d] = su / sl;
}

extern "C" void kernel_launch(void* const* d_in, const int* in_sizes, int n_in,
                              void* d_out, int out_size, void* d_ws, size_t ws_size,
                              hipStream_t stream) {
  const float* q = (const float*)d_in[0];
  const float* k = (const float*)d_in[1];
  const float* v = (const float*)d_in[2];
  float* outp = (float*)d_out;

  const size_t per_split = (size_t)128 * SQ_ * D_ * 4 + (size_t)128 * SQ_ * 4; // U + l
  int nsplit = 1;
  if (ws_size >= 4 * per_split) nsplit = 4;       // 512 blocks of 512 thr = 2/CU resident
  else if (ws_size >= 2 * per_split) nsplit = 2;

  float* Ubase = (float*)d_ws;
  float* Lbase = Ubase + (size_t)nsplit * 128 * SQ_ * D_;

  dim3 grid(128, nsplit);
  mha_split_kernel<<<grid, 512, 0, stream>>>(q, k, v, Ubase, Lbase, outp, nsplit);
  if (nsplit > 1) {
    mha_combine_kernel<<<(128 * SQ_ * D_) / 256, 256, 0, stream>>>(Ubase, Lbase, outp, nsplit);
  }
}